// Round 1
// baseline (2446.023 us; speedup 1.0000x reference)
//
#include <hip/hip_runtime.h>
#include <math.h>

// Problem dims
#define Bb 256
#define Rr 6
#define Ksp 49
#define Cc 512
#define Hh 1024
#define Ee 300
#define NN (Bb*Rr)        // 1536
#define NLl 2001

// ---------------- generic fp32 GEMM: C = act(A@B + bias) ----------------
// amode 0: A row-major [M,K]
// amode 1: A is v_org [B,512,49]; logical A[m,c] = v_org[b,c,k], m=b*49+k
#define TBM 64
#define TBN 64
#define TBK 16

__global__ void __launch_bounds__(256) gemm_f32(
    const float* __restrict__ A, const float* __restrict__ Bm,
    const float* __restrict__ bias, float* __restrict__ C,
    int M, int N, int K, int amode, int act)
{
    __shared__ float As[TBK][TBM + 1];
    __shared__ float Bs[TBK][TBN];
    const int bm = blockIdx.y * TBM;
    const int bn = blockIdx.x * TBN;
    const int tid = threadIdx.x;
    const int tx = tid & 15, ty = tid >> 4;
    const int a_r = tid >> 2;            // 0..63
    const int a_c = (tid & 3) << 2;      // 0,4,8,12
    const int b_r = tid >> 4;            // 0..15
    const int b_c = (tid & 15) << 2;     // 0..60
    float acc[4][4] = {{0.f}};

    for (int kt = 0; kt < K; kt += TBK) {
        // ---- A tile ----
        {
            const int gm = bm + a_r;
            const int kb = kt + a_c;
            if (gm < M) {
                if (amode == 0) {
                    if (kb + 3 < K) {
                        const float4 v = *(const float4*)(A + (size_t)gm * K + kb);
                        As[a_c + 0][a_r] = v.x; As[a_c + 1][a_r] = v.y;
                        As[a_c + 2][a_r] = v.z; As[a_c + 3][a_r] = v.w;
                    } else {
                        #pragma unroll
                        for (int j = 0; j < 4; j++)
                            As[a_c + j][a_r] = (kb + j < K) ? A[(size_t)gm * K + kb + j] : 0.f;
                    }
                } else {
                    const int bb = gm / Ksp, ks = gm - bb * Ksp;
                    const float* base = A + (size_t)bb * Cc * Ksp + ks;
                    #pragma unroll
                    for (int j = 0; j < 4; j++) {
                        const int c = kb + j;
                        As[a_c + j][a_r] = (c < K) ? base[(size_t)c * Ksp] : 0.f;
                    }
                }
            } else {
                #pragma unroll
                for (int j = 0; j < 4; j++) As[a_c + j][a_r] = 0.f;
            }
        }
        // ---- B tile ----
        {
            const int gk = kt + b_r;
            const int gn = bn + b_c;
            if (gk < K) {
                const float* bp = Bm + (size_t)gk * N + gn;
                #pragma unroll
                for (int j = 0; j < 4; j++)
                    Bs[b_r][b_c + j] = (gn + j < N) ? bp[j] : 0.f;
            } else {
                #pragma unroll
                for (int j = 0; j < 4; j++) Bs[b_r][b_c + j] = 0.f;
            }
        }
        __syncthreads();
        #pragma unroll
        for (int kk = 0; kk < TBK; kk++) {
            const float a0 = As[kk][ty * 4 + 0], a1 = As[kk][ty * 4 + 1];
            const float a2 = As[kk][ty * 4 + 2], a3 = As[kk][ty * 4 + 3];
            const float b0 = Bs[kk][tx * 4 + 0], b1 = Bs[kk][tx * 4 + 1];
            const float b2 = Bs[kk][tx * 4 + 2], b3 = Bs[kk][tx * 4 + 3];
            acc[0][0] += a0 * b0; acc[0][1] += a0 * b1; acc[0][2] += a0 * b2; acc[0][3] += a0 * b3;
            acc[1][0] += a1 * b0; acc[1][1] += a1 * b1; acc[1][2] += a1 * b2; acc[1][3] += a1 * b3;
            acc[2][0] += a2 * b0; acc[2][1] += a2 * b1; acc[2][2] += a2 * b2; acc[2][3] += a2 * b3;
            acc[3][0] += a3 * b0; acc[3][1] += a3 * b1; acc[3][2] += a3 * b2; acc[3][3] += a3 * b3;
        }
        __syncthreads();
    }
    #pragma unroll
    for (int i = 0; i < 4; i++) {
        const int gm = bm + ty * 4 + i;
        if (gm >= M) continue;
        #pragma unroll
        for (int j = 0; j < 4; j++) {
            const int gn = bn + tx * 4 + j;
            if (gn >= N) continue;
            float v = acc[i][j];
            if (bias) v += bias[gn];
            if (act) v = fmaxf(v, 0.f);
            C[(size_t)gm * N + gn] = v;
        }
    }
}

// ---------------- gather rv = [verb_e | role_e] ----------------
__global__ void gather_rv(const float* __restrict__ verb_table,
                          const float* __restrict__ role_table,
                          const int* __restrict__ gt_verb,
                          const int* __restrict__ role_idx,
                          float* __restrict__ rv)
{
    const int idx = blockIdx.x * 256 + threadIdx.x;
    const int total = NN * (2 * Ee);
    if (idx >= total) return;
    const int n = idx / (2 * Ee);
    const int col = idx - n * (2 * Ee);
    const int b = n / Rr, r = n - b * Rr;
    float v;
    if (col < Ee) v = verb_table[(size_t)gt_verb[b] * Ee + col];
    else          v = role_table[(size_t)role_idx[b * Rr + r] * Ee + (col - Ee)];
    rv[idx] = v;
}

// ---------------- fused attention: logits -> softmax -> weighted img sum ----
// Vh:   [B*49, H]   relu(img@av_W+av_b), shared across roles
// Q:    [N, H]      relu'd query
// IMG:  mode 0 -> v_org [B,512,49]; mode 1 -> img_feat [B,49,512]
// Vemb: [N, 512]
__global__ void __launch_bounds__(256) att_kernel(
    const float* __restrict__ Vh, const float* __restrict__ Q,
    const float* __restrict__ aoW, const float* __restrict__ aoB,
    const float* __restrict__ IMG, float* __restrict__ Vemb, int mode)
{
    const int n = blockIdx.x;         // 0..N-1
    const int b = n / Rr;
    const int tid = threadIdx.x;
    __shared__ float s_q[Hh];
    __shared__ float s_log[64];
    __shared__ float s_att[Ksp];

    for (int h = tid; h < Hh; h += 256) s_q[h] = Q[(size_t)n * Hh + h] * aoW[h];
    __syncthreads();

    const int wave = tid >> 6, lane = tid & 63;
    const float aob = aoB[0];
    for (int k = wave; k < Ksp; k += 4) {
        const float* vp = Vh + ((size_t)b * Ksp + k) * Hh;
        float sum = 0.f;
        for (int h = lane; h < Hh; h += 64) sum += vp[h] * s_q[h];
        #pragma unroll
        for (int off = 32; off; off >>= 1) sum += __shfl_down(sum, off);
        if (lane == 0) s_log[k] = sum + aob;
    }
    __syncthreads();

    if (tid < 64) {
        float v = (tid < Ksp) ? s_log[tid] : -INFINITY;
        float m = v;
        #pragma unroll
        for (int off = 32; off; off >>= 1) m = fmaxf(m, __shfl_down(m, off));
        m = __shfl(m, 0);
        float e = (tid < Ksp) ? expf(v - m) : 0.f;
        float s = e;
        #pragma unroll
        for (int off = 32; off; off >>= 1) s += __shfl_down(s, off);
        s = __shfl(s, 0);
        if (tid < Ksp) s_att[tid] = e / s;
    }
    __syncthreads();

    for (int c = tid; c < Cc; c += 256) {
        float acc = 0.f;
        if (mode == 0) {
            const float* ip = IMG + (size_t)b * Cc * Ksp + (size_t)c * Ksp;
            #pragma unroll 7
            for (int k = 0; k < Ksp; k++) acc += s_att[k] * ip[k];
        } else {
            const float* ip = IMG + (size_t)b * Ksp * Cc + c;
            #pragma unroll 7
            for (int k = 0; k < Ksp; k++) acc += s_att[k] * ip[(size_t)k * Cc];
        }
        Vemb[(size_t)n * Cc + c] = acc;
    }
}

// ---------------- MFB: signed-sqrt + row L2 normalize ----------------
__global__ void __launch_bounds__(256) mfb_kernel(
    const float* __restrict__ q, const float* __restrict__ v, float* __restrict__ out)
{
    const int n = blockIdx.x;
    const int tid = threadIdx.x;
    __shared__ float red[4];
    float sv[4];
    float local = 0.f;
    #pragma unroll
    for (int i = 0; i < 4; i++) {
        const int h = tid + i * 256;
        const float z = q[(size_t)n * Hh + h] * v[(size_t)n * Hh + h];
        const float s = (z > 0.f) ? sqrtf(z) : -sqrtf(-z);
        sv[i] = s;
        local += s * s;
    }
    #pragma unroll
    for (int off = 32; off; off >>= 1) local += __shfl_down(local, off);
    if ((tid & 63) == 0) red[tid >> 6] = local;
    __syncthreads();
    const float tot = red[0] + red[1] + red[2] + red[3];
    const float inv = 1.f / fmaxf(sqrtf(tot), 1e-12f);
    #pragma unroll
    for (int i = 0; i < 4; i++) out[(size_t)n * Hh + tid + i * 256] = sv[i] * inv;
}

// ---------------- neighbor attention over roles (per batch) ----------------
__global__ void __launch_bounds__(256) nattn_kernel(
    const float* __restrict__ qh, const float* __restrict__ kh,
    const float* __restrict__ vh, const int* __restrict__ mask,
    float* __restrict__ nv)
{
    const int b = blockIdx.x;
    const int tid = threadIdx.x;
    __shared__ float s_sc[Rr][Rr];
    __shared__ float s_at[Rr][Rr];
    const int wave = tid >> 6, lane = tid & 63;
    for (int p = wave; p < Rr * Rr; p += 4) {
        const int i = p / Rr, j = p - (p / Rr) * Rr;
        const float* qp = qh + ((size_t)b * Rr + i) * Hh;
        const float* kp = kh + ((size_t)b * Rr + j) * Hh;
        float s = 0.f;
        for (int h = lane; h < Hh; h += 64) s += qp[h] * kp[h];
        #pragma unroll
        for (int off = 32; off; off >>= 1) s += __shfl_down(s, off);
        if (lane == 0) s_sc[i][j] = s * 0.03125f;  // 1/sqrt(1024)
    }
    __syncthreads();
    if (tid < Rr) {
        const int i = tid;
        float vals[Rr];
        float m = -INFINITY;
        #pragma unroll
        for (int j = 0; j < Rr; j++) {
            const float mij = (i == j) ? 0.f : (float)mask[b * Rr * Rr + i * Rr + j];
            const float v = (mij > 0.f) ? s_sc[i][j] : -1e9f;
            vals[j] = v;
            m = fmaxf(m, v);
        }
        float ssum = 0.f;
        #pragma unroll
        for (int j = 0; j < Rr; j++) { const float e = expf(vals[j] - m); s_at[i][j] = e; ssum += e; }
        const float invs = 1.f / ssum;
        #pragma unroll
        for (int j = 0; j < Rr; j++) s_at[i][j] *= invs;
    }
    __syncthreads();
    for (int h = tid; h < Hh; h += 256) {
        #pragma unroll
        for (int i = 0; i < Rr; i++) {
            float acc = 0.f;
            #pragma unroll
            for (int j = 0; j < Rr; j++)
                acc += s_at[i][j] * vh[((size_t)b * Rr + j) * Hh + h];
            nv[((size_t)b * Rr + i) * Hh + h] = acc;
        }
    }
}

// ---------------- concat [neigh | rv] ----------------
__global__ void concat_kernel(const float* __restrict__ neigh,
                              const float* __restrict__ rv,
                              float* __restrict__ cat)
{
    const int idx = blockIdx.x * 256 + threadIdx.x;
    const int W = Hh + 2 * Ee;   // 1624
    const int total = NN * W;
    if (idx >= total) return;
    const int m = idx / W;
    const int k = idx - m * W;
    cat[idx] = (k < Hh) ? neigh[(size_t)m * Hh + k] : rv[(size_t)m * (2 * Ee) + (k - Hh)];
}

// ---------------- gate + tanh mix ----------------
__global__ void gate_kernel(const float* __restrict__ out2,
                            const float* __restrict__ out_verb,
                            const float* __restrict__ ans0,
                            float* __restrict__ out_f, int total)
{
    const int i = blockIdx.x * 256 + threadIdx.x;
    if (i >= total) return;
    const float o2 = out2[i], ov = out_verb[i], a0 = ans0[i];
    const float g = 1.f / (1.f + expf(-(o2 + ov)));
    out_f[i] = (1.f - g) * ov + g * tanhf(o2 + a0);
}

extern "C" void kernel_launch(void* const* d_in, const int* in_sizes, int n_in,
                              void* d_out, int out_size, void* d_ws, size_t ws_size,
                              hipStream_t stream)
{
    const float* v_org      = (const float*)d_in[0];
    const float* img_feat   = (const float*)d_in[1];
    const int*   gt_verb    = (const int*)d_in[2];
    const int*   role_idx   = (const int*)d_in[3];
    const int*   mask       = (const int*)d_in[4];
    const float* verb_table = (const float*)d_in[5];
    const float* role_table = (const float*)d_in[6];
    const float* qc_W  = (const float*)d_in[7];
    const float* qc_b  = (const float*)d_in[8];
    const float* av_W  = (const float*)d_in[9];
    const float* av_b  = (const float*)d_in[10];
    const float* aq_W  = (const float*)d_in[11];
    const float* aq_b  = (const float*)d_in[12];
    const float* ao_W  = (const float*)d_in[13];
    const float* ao_b  = (const float*)d_in[14];
    const float* vn_W  = (const float*)d_in[15];
    const float* vn_b  = (const float*)d_in[16];
    const float* qn_W  = (const float*)d_in[17];
    const float* qn_b  = (const float*)d_in[18];
    const float* Wq    = (const float*)d_in[19];
    const float* Wk    = (const float*)d_in[20];
    const float* Wv    = (const float*)d_in[21];
    const float* Wo    = (const float*)d_in[22];
    const float* uqc_W = (const float*)d_in[23];
    const float* uqc_b = (const float*)d_in[24];
    const float* cls_W = (const float*)d_in[25];
    const float* cls_b = (const float*)d_in[26];
    float* out = (float*)d_out;

    float* ws = (float*)d_ws;
    size_t o = 0;
    const size_t MI = (size_t)Bb * Ksp * Hh;   // 12544*1024
    const size_t NH = (size_t)NN * Hh;         // 1536*1024
    float* v_img  = ws + o; o += MI;
    float* pool   = ws + o; o += MI;           // v_imgv, later qh..out_f
    float* rv     = ws + o; o += (size_t)NN * 2 * Ee;
    float* cat    = ws + o; o += (size_t)NN * (Hh + 2 * Ee);
    float* q_emb  = ws + o; o += NH;
    float* q_att  = ws + o; o += NH;           // reused as q_att2
    float* q_rep  = ws + o; o += NH;           // reused as q_rep2
    float* v_emb  = ws + o; o += (size_t)NN * Cc;  // reused 3x
    float* v_rep  = ws + o; o += NH;           // reused 3x
    float* out_a0 = ws + o; o += NH;
    float* out_vb = ws + o; o += NH;

    float* v_imgv = pool;
    float* qh    = pool + 0 * NH;
    float* kh    = pool + 1 * NH;
    float* vh    = pool + 2 * NH;
    float* nv    = pool + 3 * NH;
    float* neigh = pool + 4 * NH;
    float* uq    = pool + 5 * NH;
    float* out2  = pool + 6 * NH;
    float* out_f = pool + 7 * NH;

    const dim3 blk(256);
    const dim3 gN24(Hh / TBN, NN / TBM);             // 16 x 24
    const dim3 gBig(Hh / TBN, (Bb * Ksp) / TBM);     // 16 x 196

    // 1. rv gather
    gather_rv<<<dim3((NN * 2 * Ee + 255) / 256), blk, 0, stream>>>(
        verb_table, role_table, gt_verb, role_idx, rv);
    // 2. q_emb = relu(rv @ qc_W + qc_b)
    gemm_f32<<<gN24, blk, 0, stream>>>(rv, qc_W, qc_b, q_emb, NN, Hh, 2 * Ee, 0, 1);
    // 3. v_img = relu(img0 @ av_W + av_b)   (img0 read transposed from v_org)
    gemm_f32<<<gBig, blk, 0, stream>>>(v_org, av_W, av_b, v_img, Bb * Ksp, Hh, Cc, 1, 1);
    // 4. v_imgv = relu(img_feat @ av_W + av_b)
    gemm_f32<<<gBig, blk, 0, stream>>>(img_feat, av_W, av_b, v_imgv, Bb * Ksp, Hh, Cc, 0, 1);
    // 5. q_att = relu(q_emb @ aq_W + aq_b)  (shared by att1 and att_v)
    gemm_f32<<<gN24, blk, 0, stream>>>(q_emb, aq_W, aq_b, q_att, NN, Hh, Hh, 0, 1);
    // 6. att1 -> v_emb
    att_kernel<<<dim3(NN), blk, 0, stream>>>(v_img, q_att, ao_W, ao_b, v_org, v_emb, 0);
    // 7. v_repr
    gemm_f32<<<gN24, blk, 0, stream>>>(v_emb, vn_W, vn_b, v_rep, NN, Hh, Cc, 0, 1);
    // 8. q_repr
    gemm_f32<<<gN24, blk, 0, stream>>>(q_emb, qn_W, qn_b, q_rep, NN, Hh, Hh, 0, 1);
    // 9. out (ans0)
    mfb_kernel<<<dim3(NN), blk, 0, stream>>>(q_rep, v_rep, out_a0);
    // 10. att_v -> v_emb
    att_kernel<<<dim3(NN), blk, 0, stream>>>(v_imgv, q_att, ao_W, ao_b, img_feat, v_emb, 1);
    // 11. v_repr_verb
    gemm_f32<<<gN24, blk, 0, stream>>>(v_emb, vn_W, vn_b, v_rep, NN, Hh, Cc, 0, 1);
    // 12. out_verb
    mfb_kernel<<<dim3(NN), blk, 0, stream>>>(q_rep, v_rep, out_vb);
    // 13. qh, kh, vh  (pool now free of v_imgv)
    gemm_f32<<<gN24, blk, 0, stream>>>(out_a0, Wq, nullptr, qh, NN, Hh, Hh, 0, 0);
    gemm_f32<<<gN24, blk, 0, stream>>>(out_a0, Wk, nullptr, kh, NN, Hh, Hh, 0, 0);
    gemm_f32<<<gN24, blk, 0, stream>>>(out_a0, Wv, nullptr, vh, NN, Hh, Hh, 0, 0);
    // 14. neighbor attention
    nattn_kernel<<<dim3(Bb), blk, 0, stream>>>(qh, kh, vh, mask, nv);
    // 15. neigh = nv @ Wo
    gemm_f32<<<gN24, blk, 0, stream>>>(nv, Wo, nullptr, neigh, NN, Hh, Hh, 0, 0);
    // 16. cat = [neigh | rv]
    concat_kernel<<<dim3((NN * (Hh + 2 * Ee) + 255) / 256), blk, 0, stream>>>(neigh, rv, cat);
    // 17. uq = relu(cat @ uqc_W + uqc_b)
    gemm_f32<<<gN24, blk, 0, stream>>>(cat, uqc_W, uqc_b, uq, NN, Hh, Hh + 2 * Ee, 0, 1);
    // 18. q_att2 = relu(uq @ aq_W + aq_b)  (reuse q_att)
    gemm_f32<<<gN24, blk, 0, stream>>>(uq, aq_W, aq_b, q_att, NN, Hh, Hh, 0, 1);
    // 19. att2 -> v_emb
    att_kernel<<<dim3(NN), blk, 0, stream>>>(v_img, q_att, ao_W, ao_b, v_org, v_emb, 0);
    // 20. v_repr2
    gemm_f32<<<gN24, blk, 0, stream>>>(v_emb, vn_W, vn_b, v_rep, NN, Hh, Cc, 0, 1);
    // 21. q_repr2 (reuse q_rep)
    gemm_f32<<<gN24, blk, 0, stream>>>(uq, qn_W, qn_b, q_rep, NN, Hh, Hh, 0, 1);
    // 22. out2
    mfb_kernel<<<dim3(NN), blk, 0, stream>>>(q_rep, v_rep, out2);
    // 23. gate mix
    gate_kernel<<<dim3((NN * Hh + 255) / 256), blk, 0, stream>>>(out2, out_vb, out_a0, out_f, NN * Hh);
    // 24. logits = out_f @ cls_W + cls_b  -> d_out
    gemm_f32<<<dim3((NLl + TBN - 1) / TBN, NN / TBM), blk, 0, stream>>>(
        out_f, cls_W, cls_b, out, NN, NLl, Hh, 0, 0);
}

// Round 2
// 858.516 us; speedup vs baseline: 2.8491x; 2.8491x over previous
//
#include <hip/hip_runtime.h>
#include <math.h>

typedef unsigned short u16;
typedef __attribute__((ext_vector_type(8))) short short8;
typedef __attribute__((ext_vector_type(4))) float f32x4;

#define Bb 256
#define Rr 6
#define Ksp 49
#define Cc 512
#define Hh 1024
#define Ee 300
#define NN (Bb*Rr)        // 1536
#define NLl 2001

__device__ __forceinline__ u16 f2b(float x) {
    union { float f; unsigned u; } c; c.f = x;
    unsigned r = c.u + 0x7fffu + ((c.u >> 16) & 1u);   // RNE, finite inputs
    return (u16)(r >> 16);
}
__device__ __forceinline__ float b2f(u16 b) {
    union { unsigned u; float f; } c; c.u = ((unsigned)b) << 16; return c.f;
}

// async global->LDS, 16B per lane; LDS dest = wave-uniform base + lane*16
#define ASYNC16(gp, lp) __builtin_amdgcn_global_load_lds( \
    (const __attribute__((address_space(1))) unsigned int*)(gp), \
    (__attribute__((address_space(3))) unsigned int*)(lp), 16, 0, 0)

// ---------------- bf16 MFMA GEMM ----------------
// A bf16 [M][K] row-major, Bt bf16 [N][K] row-major (= B^T), K % 32 == 0.
// C = act(A@B + bias); writes fp32 (Cf) and/or bf16 (Cb), row stride ldc,
// cols >= Nreal skipped. Tile: BM=32*WM x BN=32*WN, 4 waves in 2x2.
// LDS is fragment-linear: sub-tile s (16 rows), lane l=q*16+m holds
// X[s*16+m][kt + q*8 .. +7] at lds[(s*64+l)*8] -> all reads/writes are
// 64-lane contiguous 1024B (conflict-free).
template<int WM, int WN>
__global__ void __launch_bounds__(256) gemm_bf16(
    const u16* __restrict__ A, const u16* __restrict__ Bt,
    const float* __restrict__ bias,
    float* __restrict__ Cf, u16* __restrict__ Cb,
    int M, int N, int K, int ldc, int Nreal, int act)
{
    constexpr int SM = 2 * WM, SN = 2 * WN;       // 16-row sub-tiles
    constexpr int BM = 16 * SM, BN = 16 * SN;
    constexpr int APW = SM / 4 > 0 ? SM / 4 : 1;  // sub-tiles staged per wave
    constexpr int BPW = SN / 4 > 0 ? SN / 4 : 1;
    __shared__ u16 lds[(SM + SN) * 64 * 8];
    const int tid  = threadIdx.x;
    const int wave = tid >> 6, lane = tid & 63;
    const int m0 = lane & 15, q0 = lane >> 4;
    const int bm = blockIdx.y * BM, bn = blockIdx.x * BN;
    const int wr = wave >> 1, wc = wave & 1;

    f32x4 acc[WM][WN];
    #pragma unroll
    for (int i = 0; i < WM; i++)
        #pragma unroll
        for (int j = 0; j < WN; j++)
            acc[i][j] = (f32x4){0.f, 0.f, 0.f, 0.f};

    for (int kt = 0; kt < K; kt += 32) {
        #pragma unroll
        for (int i = 0; i < APW; i++) {
            const int s = wave * APW + i;
            const u16* g = A + (size_t)(bm + s * 16 + m0) * K + kt + q0 * 8;
            ASYNC16(g, &lds[(s * 64) * 8]);
        }
        #pragma unroll
        for (int i = 0; i < BPW; i++) {
            const int s = wave * BPW + i;
            const u16* g = Bt + (size_t)(bn + s * 16 + m0) * K + kt + q0 * 8;
            ASYNC16(g, &lds[((SM + s) * 64) * 8]);
        }
        __syncthreads();
        short8 af[WM], bfr[WN];
        #pragma unroll
        for (int i = 0; i < WM; i++)
            af[i] = *(const short8*)&lds[((wr * WM + i) * 64 + lane) * 8];
        #pragma unroll
        for (int j = 0; j < WN; j++)
            bfr[j] = *(const short8*)&lds[((SM + wc * WN + j) * 64 + lane) * 8];
        #pragma unroll
        for (int i = 0; i < WM; i++)
            #pragma unroll
            for (int j = 0; j < WN; j++)
                acc[i][j] = __builtin_amdgcn_mfma_f32_16x16x32_bf16(
                    af[i], bfr[j], acc[i][j], 0, 0, 0);
        __syncthreads();
    }

    // epilogue: D[row = q0*4 + r][col = m0] per 16x16 tile (m89/m91 layout)
    #pragma unroll
    for (int i = 0; i < WM; i++) {
        #pragma unroll
        for (int j = 0; j < WN; j++) {
            const int col = bn + (wc * WN + j) * 16 + m0;
            if (col >= Nreal) continue;
            const float bv = bias ? bias[col] : 0.f;
            #pragma unroll
            for (int r = 0; r < 4; r++) {
                const int row = bm + (wr * WM + i) * 16 + q0 * 4 + r;
                float v = acc[i][j][r] + bv;
                if (act) v = fmaxf(v, 0.f);
                if (Cf) Cf[(size_t)row * ldc + col] = v;
                if (Cb) Cb[(size_t)row * ldc + col] = f2b(v);
            }
        }
    }
}

// ---------------- weight transpose + cast: W [K][N] f32 -> Wt [Np][Kp] bf16
__global__ void __launch_bounds__(256) transpose_cast(
    const float* __restrict__ W, u16* __restrict__ Wt,
    int K, int N, int Kp, int Np)
{
    __shared__ float s[32][33];
    const int kt = blockIdx.x * 32, nt = blockIdx.y * 32;
    const int tx = threadIdx.x & 31, ty = threadIdx.x >> 5;   // 8 rows/pass
    for (int i = ty; i < 32; i += 8) {
        const int k = kt + i, n = nt + tx;
        s[i][tx] = (k < K && n < N) ? W[(size_t)k * N + n] : 0.f;
    }
    __syncthreads();
    for (int i = ty; i < 32; i += 8) {
        const int n = nt + i, k = kt + tx;
        if (n < Np && k < Kp) Wt[(size_t)n * Kp + k] = f2b(s[tx][i]);
    }
}

// ---------------- v_org [B][C][49] -> A1 bf16 [B*49][512] (transpose-cast)
__global__ void __launch_bounds__(256) cast_img0(
    const float* __restrict__ v_org, u16* __restrict__ A1)
{
    __shared__ float s[64][50];
    const int b = blockIdx.x, c0 = blockIdx.y * 64;
    const int t = threadIdx.x;
    {
        const int ci = t >> 2, k0 = t & 3;
        const float* p = v_org + ((size_t)b * Cc + c0 + ci) * Ksp;
        for (int k = k0; k < Ksp; k += 4) s[ci][k] = p[k];
    }
    __syncthreads();
    {
        const int cc = t & 63, kb = t >> 6;
        for (int k = kb; k < Ksp; k += 4)
            A1[((size_t)b * Ksp + k) * Cc + c0 + cc] = f2b(s[cc][k]);
    }
}

// ---------------- elementwise f32 -> bf16 (x4) ----------------
__global__ void cast_f2b4(const float* __restrict__ x, u16* __restrict__ y, int n4)
{
    const int i = blockIdx.x * 256 + threadIdx.x;
    if (i >= n4) return;
    const float4 v = ((const float4*)x)[i];
    ushort4 o;
    o.x = f2b(v.x); o.y = f2b(v.y); o.z = f2b(v.z); o.w = f2b(v.w);
    ((ushort4*)y)[i] = o;
}

// ---------------- rv = [verb_e | role_e] -> bf16 [NN][608] (pad 600..607 = 0)
__global__ void gather_rv(const float* __restrict__ verb_table,
                          const float* __restrict__ role_table,
                          const int* __restrict__ gt_verb,
                          const int* __restrict__ role_idx,
                          u16* __restrict__ rv)
{
    const int idx = blockIdx.x * 256 + threadIdx.x;
    const int total = NN * 608;
    if (idx >= total) return;
    const int n = idx / 608;
    const int col = idx - n * 608;
    const int b = n / Rr, r = n - b * Rr;
    float v = 0.f;
    if (col < Ee)          v = verb_table[(size_t)gt_verb[b] * Ee + col];
    else if (col < 2 * Ee) v = role_table[(size_t)role_idx[b * Rr + r] * Ee + (col - Ee)];
    rv[idx] = f2b(v);
}

// ---------------- fused attention (bf16 Vh/Q, fp32 softmax, bf16 out) -----
__global__ void __launch_bounds__(256) att_kernel(
    const u16* __restrict__ Vh, const u16* __restrict__ Q,
    const float* __restrict__ aoW, const float* __restrict__ aoB,
    const float* __restrict__ IMG, u16* __restrict__ Vemb, int mode)
{
    const int n = blockIdx.x;
    const int b = n / Rr;
    const int tid = threadIdx.x;
    __shared__ float s_q[Hh];
    __shared__ float s_log[64];
    __shared__ float s_att[Ksp];

    for (int h = tid; h < Hh; h += 256) s_q[h] = b2f(Q[(size_t)n * Hh + h]) * aoW[h];
    __syncthreads();

    const int wave = tid >> 6, lane = tid & 63;
    const float aob = aoB[0];
    for (int k = wave; k < Ksp; k += 4) {
        const u16* vp = Vh + ((size_t)b * Ksp + k) * Hh;
        float sum = 0.f;
        for (int h = lane * 4; h < Hh; h += 256) {
            const ushort4 vv = *(const ushort4*)(vp + h);
            const float4 qq = *(const float4*)(s_q + h);
            sum += b2f(vv.x) * qq.x + b2f(vv.y) * qq.y
                 + b2f(vv.z) * qq.z + b2f(vv.w) * qq.w;
        }
        #pragma unroll
        for (int off = 32; off; off >>= 1) sum += __shfl_down(sum, off);
        if (lane == 0) s_log[k] = sum + aob;
    }
    __syncthreads();

    if (tid < 64) {
        float v = (tid < Ksp) ? s_log[tid] : -INFINITY;
        float m = v;
        #pragma unroll
        for (int off = 32; off; off >>= 1) m = fmaxf(m, __shfl_down(m, off));
        m = __shfl(m, 0);
        float e = (tid < Ksp) ? expf(v - m) : 0.f;
        float s = e;
        #pragma unroll
        for (int off = 32; off; off >>= 1) s += __shfl_down(s, off);
        s = __shfl(s, 0);
        if (tid < Ksp) s_att[tid] = e / s;
    }
    __syncthreads();

    for (int c = tid; c < Cc; c += 256) {
        float acc = 0.f;
        if (mode == 0) {
            const float* ip = IMG + (size_t)b * Cc * Ksp + (size_t)c * Ksp;
            #pragma unroll 7
            for (int k = 0; k < Ksp; k++) acc += s_att[k] * ip[k];
        } else {
            const float* ip = IMG + (size_t)b * Ksp * Cc + c;
            #pragma unroll 7
            for (int k = 0; k < Ksp; k++) acc += s_att[k] * ip[(size_t)k * Cc];
        }
        Vemb[(size_t)n * Cc + c] = f2b(acc);
    }
}

// ---------------- MFB: signed-sqrt + L2 norm; fp32 out + optional bf16 ----
__global__ void __launch_bounds__(256) mfb_kernel(
    const float* __restrict__ q, const float* __restrict__ v,
    float* __restrict__ outf, u16* __restrict__ outb)
{
    const int n = blockIdx.x;
    const int tid = threadIdx.x;
    __shared__ float red[4];
    float sv[4];
    float local = 0.f;
    #pragma unroll
    for (int i = 0; i < 4; i++) {
        const int h = tid + i * 256;
        const float z = q[(size_t)n * Hh + h] * v[(size_t)n * Hh + h];
        const float s = (z > 0.f) ? sqrtf(z) : -sqrtf(-z);
        sv[i] = s;
        local += s * s;
    }
    #pragma unroll
    for (int off = 32; off; off >>= 1) local += __shfl_down(local, off);
    if ((tid & 63) == 0) red[tid >> 6] = local;
    __syncthreads();
    const float tot = red[0] + red[1] + red[2] + red[3];
    const float inv = 1.f / fmaxf(sqrtf(tot), 1e-12f);
    #pragma unroll
    for (int i = 0; i < 4; i++) {
        const float o = sv[i] * inv;
        const size_t off2 = (size_t)n * Hh + tid + i * 256;
        outf[off2] = o;
        if (outb) outb[off2] = f2b(o);
    }
}

// ---------------- neighbor attention (reads fused qkv [NN][3072]) ---------
__global__ void __launch_bounds__(256) nattn_kernel(
    const float* __restrict__ qkv, const int* __restrict__ mask,
    u16* __restrict__ nv)
{
    const int b = blockIdx.x;
    const int tid = threadIdx.x;
    __shared__ float s_sc[Rr][Rr];
    __shared__ float s_at[Rr][Rr];
    const int wave = tid >> 6, lane = tid & 63;
    for (int p = wave; p < Rr * Rr; p += 4) {
        const int i = p / Rr, j = p - (p / Rr) * Rr;
        const float* qp = qkv + ((size_t)(b * Rr + i)) * 3072;
        const float* kp = qkv + ((size_t)(b * Rr + j)) * 3072 + 1024;
        float s = 0.f;
        for (int h = lane; h < Hh; h += 64) s += qp[h] * kp[h];
        #pragma unroll
        for (int off = 32; off; off >>= 1) s += __shfl_down(s, off);
        if (lane == 0) s_sc[i][j] = s * 0.03125f;   // 1/sqrt(1024)
    }
    __syncthreads();
    if (tid < Rr) {
        const int i = tid;
        float vals[Rr];
        float m = -INFINITY;
        #pragma unroll
        for (int j = 0; j < Rr; j++) {
            const float mij = (i == j) ? 0.f : (float)mask[b * Rr * Rr + i * Rr + j];
            const float v = (mij > 0.f) ? s_sc[i][j] : -1e9f;
            vals[j] = v;
            m = fmaxf(m, v);
        }
        float ssum = 0.f;
        #pragma unroll
        for (int j = 0; j < Rr; j++) { const float e = expf(vals[j] - m); s_at[i][j] = e; ssum += e; }
        const float invs = 1.f / ssum;
        #pragma unroll
        for (int j = 0; j < Rr; j++) s_at[i][j] *= invs;
    }
    __syncthreads();
    for (int h = tid; h < Hh; h += 256) {
        #pragma unroll
        for (int i = 0; i < Rr; i++) {
            float acc = 0.f;
            #pragma unroll
            for (int j = 0; j < Rr; j++)
                acc += s_at[i][j] * qkv[((size_t)(b * Rr + j)) * 3072 + 2048 + h];
            nv[((size_t)(b * Rr + i)) * Hh + h] = f2b(acc);
        }
    }
}

// ---------------- cat = [neigh(1024) | rv(600)] -> bf16 [NN][1632] --------
__global__ void concat_kernel(const u16* __restrict__ neigh,
                              const u16* __restrict__ rv,
                              u16* __restrict__ cat)
{
    const int idx = blockIdx.x * 256 + threadIdx.x;
    const int W = 1632;
    const int total = NN * W;
    if (idx >= total) return;
    const int m = idx / W;
    const int k = idx - m * W;
    u16 v = 0;
    if (k < Hh)                 v = neigh[(size_t)m * Hh + k];
    else if (k < Hh + 2 * Ee)   v = rv[(size_t)m * 608 + (k - Hh)];
    cat[idx] = v;
}

// ---------------- gate + tanh mix -> bf16 out_f ----------------
__global__ void gate_kernel(const float* __restrict__ out2,
                            const float* __restrict__ out_verb,
                            const float* __restrict__ ans0,
                            u16* __restrict__ out_f, int total)
{
    const int i = blockIdx.x * 256 + threadIdx.x;
    if (i >= total) return;
    const float o2 = out2[i], ov = out_verb[i], a0 = ans0[i];
    const float g = 1.f / (1.f + expf(-(o2 + ov)));
    out_f[i] = f2b((1.f - g) * ov + g * tanhf(o2 + a0));
}

extern "C" void kernel_launch(void* const* d_in, const int* in_sizes, int n_in,
                              void* d_out, int out_size, void* d_ws, size_t ws_size,
                              hipStream_t stream)
{
    const float* v_org      = (const float*)d_in[0];
    const float* img_feat   = (const float*)d_in[1];
    const int*   gt_verb    = (const int*)d_in[2];
    const int*   role_idx   = (const int*)d_in[3];
    const int*   mask       = (const int*)d_in[4];
    const float* verb_table = (const float*)d_in[5];
    const float* role_table = (const float*)d_in[6];
    const float* qc_W  = (const float*)d_in[7];
    const float* qc_b  = (const float*)d_in[8];
    const float* av_W  = (const float*)d_in[9];
    const float* av_b  = (const float*)d_in[10];
    const float* aq_W  = (const float*)d_in[11];
    const float* aq_b  = (const float*)d_in[12];
    const float* ao_W  = (const float*)d_in[13];
    const float* ao_b  = (const float*)d_in[14];
    const float* vn_W  = (const float*)d_in[15];
    const float* vn_b  = (const float*)d_in[16];
    const float* qn_W  = (const float*)d_in[17];
    const float* qn_b  = (const float*)d_in[18];
    const float* Wq    = (const float*)d_in[19];
    const float* Wk    = (const float*)d_in[20];
    const float* Wv    = (const float*)d_in[21];
    const float* Wo    = (const float*)d_in[22];
    const float* uqc_W = (const float*)d_in[23];
    const float* uqc_b = (const float*)d_in[24];
    const float* cls_W = (const float*)d_in[25];
    const float* cls_b = (const float*)d_in[26];
    float* out = (float*)d_out;

    // ---- workspace layout (bytes, 256-aligned) ----
    char* base = (char*)d_ws;
    size_t off = 0;
    auto alloc = [&](size_t bytes) -> char* {
        char* p = base + off;
        off += (bytes + 255) & ~(size_t)255;
        return p;
    };
    u16* wt_qc  = (u16*)alloc((size_t)1024 * 608 * 2);
    u16* wt_av  = (u16*)alloc((size_t)1024 * 512 * 2);
    u16* wt_aq  = (u16*)alloc((size_t)1024 * 1024 * 2);
    u16* wt_vn  = (u16*)alloc((size_t)1024 * 512 * 2);
    u16* wt_qn  = (u16*)alloc((size_t)1024 * 1024 * 2);
    u16* wt_qkv = (u16*)alloc((size_t)3072 * 1024 * 2);
    u16* wt_wo  = (u16*)alloc((size_t)1024 * 1024 * 2);
    u16* wt_uqc = (u16*)alloc((size_t)1024 * 1632 * 2);
    u16* wt_cls = (u16*)alloc((size_t)2048 * 1024 * 2);
    // P1: A1+A2 (each 12544*512 u16); later aliased by qkv fp32 [NN][3072]
    char* P1 = alloc((size_t)12544 * 512 * 2 * 2);
    u16* A1 = (u16*)P1;
    u16* A2 = (u16*)(P1 + (size_t)12544 * 512 * 2);
    float* qkv = (float*)P1;                       // 18.9MB <= 25.7MB
    u16* v_img = (u16*)alloc((size_t)12544 * 1024 * 2);
    // P2: v_imgv; after att_v done, aliased by nv/neigh/cat/uq/out_f/out2
    char* P2 = alloc((size_t)12544 * 1024 * 2);
    u16* v_imgv = (u16*)P2;
    u16* nv     = (u16*)(P2 + 0);
    u16* neigh  = (u16*)(P2 + 3145728);
    u16* cat    = (u16*)(P2 + 6291456);
    u16* uq     = (u16*)(P2 + 11304960);
    u16* out_f  = (u16*)(P2 + 14450688);
    float* out2 = (float*)(P2 + 17596416);
    u16* rv     = (u16*)alloc((size_t)NN * 608 * 2);
    u16* q_emb  = (u16*)alloc((size_t)NN * 1024 * 2);
    u16* q_att  = (u16*)alloc((size_t)NN * 1024 * 2);
    u16* v_emb  = (u16*)alloc((size_t)NN * 512 * 2);
    float* q_rep = (float*)alloc((size_t)NN * 1024 * 4);
    float* v_rep = (float*)alloc((size_t)NN * 1024 * 4);
    float* a0f   = (float*)alloc((size_t)NN * 1024 * 4);
    u16*   a0b   = (u16*)alloc((size_t)NN * 1024 * 2);
    float* vbf   = (float*)alloc((size_t)NN * 1024 * 4);

    const dim3 blk(256);

    // ---- weight transposes (bf16 B^T, zero-padded) ----
    transpose_cast<<<dim3(19, 32), blk, 0, stream>>>(qc_W,  wt_qc,  600, 1024, 608, 1024);
    transpose_cast<<<dim3(16, 32), blk, 0, stream>>>(av_W,  wt_av,  512, 1024, 512, 1024);
    transpose_cast<<<dim3(32, 32), blk, 0, stream>>>(aq_W,  wt_aq,  1024, 1024, 1024, 1024);
    transpose_cast<<<dim3(16, 32), blk, 0, stream>>>(vn_W,  wt_vn,  512, 1024, 512, 1024);
    transpose_cast<<<dim3(32, 32), blk, 0, stream>>>(qn_W,  wt_qn,  1024, 1024, 1024, 1024);
    transpose_cast<<<dim3(32, 32), blk, 0, stream>>>(Wq, wt_qkv,               1024, 1024, 1024, 1024);
    transpose_cast<<<dim3(32, 32), blk, 0, stream>>>(Wk, wt_qkv + 1024 * 1024, 1024, 1024, 1024, 1024);
    transpose_cast<<<dim3(32, 32), blk, 0, stream>>>(Wv, wt_qkv + 2048 * 1024, 1024, 1024, 1024, 1024);
    transpose_cast<<<dim3(32, 32), blk, 0, stream>>>(Wo,    wt_wo,  1024, 1024, 1024, 1024);
    transpose_cast<<<dim3(51, 32), blk, 0, stream>>>(uqc_W, wt_uqc, 1624, 1024, 1632, 1024);
    transpose_cast<<<dim3(32, 64), blk, 0, stream>>>(cls_W, wt_cls, 1024, 2001, 1024, 2048);

    // ---- input prep ----
    gather_rv<<<dim3((NN * 608 + 255) / 256), blk, 0, stream>>>(
        verb_table, role_table, gt_verb, role_idx, rv);
    cast_img0<<<dim3(Bb, 8), blk, 0, stream>>>(v_org, A1);
    cast_f2b4<<<dim3((12544 * 512 / 4 + 255) / 256), blk, 0, stream>>>(
        img_feat, A2, 12544 * 512 / 4);

    // ---- GEMM chain ----
    // q_emb = relu(rv @ qc_W + b)
    gemm_bf16<2,2><<<dim3(16, 24), blk, 0, stream>>>(rv, wt_qc, qc_b, nullptr, q_emb,
                                                     NN, 1024, 608, 1024, 1024, 1);
    // v_img = relu(img0 @ av_W + b)   [12544,1024,512]
    gemm_bf16<4,4><<<dim3(8, 98), blk, 0, stream>>>(A1, wt_av, av_b, nullptr, v_img,
                                                    12544, 1024, 512, 1024, 1024, 1);
    // v_imgv = relu(img_feat @ av_W + b)
    gemm_bf16<4,4><<<dim3(8, 98), blk, 0, stream>>>(A2, wt_av, av_b, nullptr, v_imgv,
                                                    12544, 1024, 512, 1024, 1024, 1);
    // q_att = relu(q_emb @ aq_W + b)
    gemm_bf16<2,2><<<dim3(16, 24), blk, 0, stream>>>(q_emb, wt_aq, aq_b, nullptr, q_att,
                                                     NN, 1024, 1024, 1024, 1024, 1);
    // att1 -> v_emb
    att_kernel<<<dim3(NN), blk, 0, stream>>>(v_img, q_att, ao_W, ao_b, v_org, v_emb, 0);
    // v_repr, q_repr (fp32 for MFB)
    gemm_bf16<2,2><<<dim3(16, 24), blk, 0, stream>>>(v_emb, wt_vn, vn_b, v_rep, nullptr,
                                                     NN, 1024, 512, 1024, 1024, 1);
    gemm_bf16<2,2><<<dim3(16, 24), blk, 0, stream>>>(q_emb, wt_qn, qn_b, q_rep, nullptr,
                                                     NN, 1024, 1024, 1024, 1024, 1);
    // out(ans0): fp32 + bf16
    mfb_kernel<<<dim3(NN), blk, 0, stream>>>(q_rep, v_rep, a0f, a0b);
    // att_v -> v_emb
    att_kernel<<<dim3(NN), blk, 0, stream>>>(v_imgv, q_att, ao_W, ao_b, img_feat, v_emb, 1);
    gemm_bf16<2,2><<<dim3(16, 24), blk, 0, stream>>>(v_emb, wt_vn, vn_b, v_rep, nullptr,
                                                     NN, 1024, 512, 1024, 1024, 1);
    // out_verb (fp32 only)
    mfb_kernel<<<dim3(NN), blk, 0, stream>>>(q_rep, v_rep, vbf, nullptr);
    // fused qkv = ans0 @ [Wq|Wk|Wv]   (P1 now free: overwrites A1/A2)
    gemm_bf16<2,2><<<dim3(48, 24), blk, 0, stream>>>(a0b, wt_qkv, nullptr, qkv, nullptr,
                                                     NN, 3072, 1024, 3072, 3072, 0);
    // neighbor attention
    nattn_kernel<<<dim3(Bb), blk, 0, stream>>>(qkv, mask, nv);
    // neigh = nv @ Wo
    gemm_bf16<2,2><<<dim3(16, 24), blk, 0, stream>>>(nv, wt_wo, nullptr, nullptr, neigh,
                                                     NN, 1024, 1024, 1024, 1024, 0);
    // cat = [neigh | rv]
    concat_kernel<<<dim3((NN * 1632 + 255) / 256), blk, 0, stream>>>(neigh, rv, cat);
    // uq = relu(cat @ uqc_W + b)
    gemm_bf16<2,2><<<dim3(16, 24), blk, 0, stream>>>(cat, wt_uqc, uqc_b, nullptr, uq,
                                                     NN, 1024, 1632, 1024, 1024, 1);
    // q_att2 = relu(uq @ aq_W + b)
    gemm_bf16<2,2><<<dim3(16, 24), blk, 0, stream>>>(uq, wt_aq, aq_b, nullptr, q_att,
                                                     NN, 1024, 1024, 1024, 1024, 1);
    // att2 -> v_emb
    att_kernel<<<dim3(NN), blk, 0, stream>>>(v_img, q_att, ao_W, ao_b, v_org, v_emb, 0);
    gemm_bf16<2,2><<<dim3(16, 24), blk, 0, stream>>>(v_emb, wt_vn, vn_b, v_rep, nullptr,
                                                     NN, 1024, 512, 1024, 1024, 1);
    gemm_bf16<2,2><<<dim3(16, 24), blk, 0, stream>>>(uq, wt_qn, qn_b, q_rep, nullptr,
                                                     NN, 1024, 1024, 1024, 1024, 1);
    // out2 (fp32 only)
    mfb_kernel<<<dim3(NN), blk, 0, stream>>>(q_rep, v_rep, out2, nullptr);
    // gate -> out_f (bf16)
    gate_kernel<<<dim3((NN * 1024 + 255) / 256), blk, 0, stream>>>(out2, vbf, a0f, out_f, NN * 1024);
    // logits = out_f @ cls_W + b  -> d_out fp32 [1536][2001]
    gemm_bf16<2,2><<<dim3(32, 24), blk, 0, stream>>>(out_f, wt_cls, cls_b, out, nullptr,
                                                     NN, 2048, 1024, 2001, 2001, 0);
}

// Round 3
// 619.330 us; speedup vs baseline: 3.9495x; 1.3862x over previous
//
#include <hip/hip_runtime.h>
#include <math.h>

typedef unsigned short u16;
typedef __attribute__((ext_vector_type(8))) short short8;
typedef __attribute__((ext_vector_type(4))) float f32x4;

#define Bb 256
#define Rr 6
#define Ksp 49
#define Cc 512
#define Hh 1024
#define Ee 300
#define NN (Bb*Rr)        // 1536
#define NLl 2001

__device__ __forceinline__ u16 f2b(float x) {
    union { float f; unsigned u; } c; c.f = x;
    unsigned r = c.u + 0x7fffu + ((c.u >> 16) & 1u);   // RNE, finite inputs
    return (u16)(r >> 16);
}
__device__ __forceinline__ float b2f(u16 b) {
    union { unsigned u; float f; } c; c.u = ((unsigned)b) << 16; return c.f;
}

// async global->LDS, 16B per lane; LDS dest = wave-uniform base + lane*16
#define ASYNC16(gp, lp) __builtin_amdgcn_global_load_lds( \
    (const __attribute__((address_space(1))) unsigned int*)(gp), \
    (__attribute__((address_space(3))) unsigned int*)(lp), 16, 0, 0)

// ---- weight-pool element offsets (bf16 B^T buffers, contiguous) ----
constexpr size_t O_QC   = 0;                         // [1024][608]
constexpr size_t O_AV   = O_QC   + (size_t)1024*608;
constexpr size_t O_AQQN = O_AV   + (size_t)1024*512; // [2048][1024] = [aq|qn]
constexpr size_t O_VN   = O_AQQN + (size_t)2048*1024;
constexpr size_t O_QKV  = O_VN   + (size_t)1024*512; // [3072][1024]
constexpr size_t O_WO   = O_QKV  + (size_t)3072*1024;
constexpr size_t O_UQC  = O_WO   + (size_t)1024*1024; // [1024][1632]
constexpr size_t O_CLS  = O_UQC  + (size_t)1024*1632; // [2048][1024]
constexpr size_t WT_ELEMS = O_CLS + (size_t)2048*1024;

// ---------------- bf16 MFMA GEMM with split bf16/fp32 epilogue ------------
// A bf16 [..][lda] row-major (K slice contiguous), Bt bf16 [N][K] (= B^T).
// col<split -> Cb bf16 (ldcb); col>=split -> Cf fp32 at col-split (ldcf).
template<int WM, int WN>
__global__ void __launch_bounds__(256) gemm_bf16(
    const u16* __restrict__ A, int lda, const u16* __restrict__ Bt,
    const float* __restrict__ bias,
    u16* __restrict__ Cb, int ldcb, float* __restrict__ Cf, int ldcf,
    int N, int K, int split, int Nreal, int act)
{
    constexpr int SM = 2 * WM, SN = 2 * WN;       // 16-row sub-tiles
    constexpr int BM = 16 * SM, BN = 16 * SN;
    constexpr int APW = SM / 4 > 0 ? SM / 4 : 1;
    constexpr int BPW = SN / 4 > 0 ? SN / 4 : 1;
    __shared__ u16 lds[(SM + SN) * 64 * 8];
    const int tid  = threadIdx.x;
    const int wave = tid >> 6, lane = tid & 63;
    const int m0 = lane & 15, q0 = lane >> 4;
    const int bm = blockIdx.y * BM, bn = blockIdx.x * BN;
    const int wr = wave >> 1, wc = wave & 1;

    f32x4 acc[WM][WN];
    #pragma unroll
    for (int i = 0; i < WM; i++)
        #pragma unroll
        for (int j = 0; j < WN; j++)
            acc[i][j] = (f32x4){0.f, 0.f, 0.f, 0.f};

    for (int kt = 0; kt < K; kt += 32) {
        #pragma unroll
        for (int i = 0; i < APW; i++) {
            const int s = wave * APW + i;
            const u16* g = A + (size_t)(bm + s * 16 + m0) * lda + kt + q0 * 8;
            ASYNC16(g, &lds[(s * 64) * 8]);
        }
        #pragma unroll
        for (int i = 0; i < BPW; i++) {
            const int s = wave * BPW + i;
            const u16* g = Bt + (size_t)(bn + s * 16 + m0) * K + kt + q0 * 8;
            ASYNC16(g, &lds[((SM + s) * 64) * 8]);
        }
        __syncthreads();
        short8 af[WM], bfr[WN];
        #pragma unroll
        for (int i = 0; i < WM; i++)
            af[i] = *(const short8*)&lds[((wr * WM + i) * 64 + lane) * 8];
        #pragma unroll
        for (int j = 0; j < WN; j++)
            bfr[j] = *(const short8*)&lds[((SM + wc * WN + j) * 64 + lane) * 8];
        #pragma unroll
        for (int i = 0; i < WM; i++)
            #pragma unroll
            for (int j = 0; j < WN; j++)
                acc[i][j] = __builtin_amdgcn_mfma_f32_16x16x32_bf16(
                    af[i], bfr[j], acc[i][j], 0, 0, 0);
        __syncthreads();
    }

    #pragma unroll
    for (int i = 0; i < WM; i++) {
        #pragma unroll
        for (int j = 0; j < WN; j++) {
            const int col = bn + (wc * WN + j) * 16 + m0;
            if (col >= Nreal) continue;
            const float bv = bias ? bias[col] : 0.f;
            #pragma unroll
            for (int r = 0; r < 4; r++) {
                const int row = bm + (wr * WM + i) * 16 + q0 * 4 + r;
                float v = acc[i][j][r] + bv;
                if (act) v = fmaxf(v, 0.f);
                if (col < split) Cb[(size_t)row * ldcb + col] = f2b(v);
                else             Cf[(size_t)row * ldcf + col - split] = v;
            }
        }
    }
}

// ---------------- unified prep kernel ----------------
// sections: [0,11456) weight transposes; [11456,15104) rv gather -> cat;
// [15104,17152) v_org transpose-cast -> A1; [17152,23424) img_feat cast -> A2;
// [23424,23432) fused aq|qn bias.
struct PrepSrc { const float* s[11]; };

__global__ void __launch_bounds__(256) prep_kernel(
    PrepSrc ps, u16* __restrict__ wt,
    const float* __restrict__ verb_table, const float* __restrict__ role_table,
    const int* __restrict__ gt_verb, const int* __restrict__ role_idx,
    u16* __restrict__ cat,
    const float* __restrict__ v_org, u16* __restrict__ A1,
    const float* __restrict__ img_feat, u16* __restrict__ A2,
    const float* __restrict__ aq_b, const float* __restrict__ qn_b,
    float* __restrict__ aqqn_b)
{
    __shared__ float sm[64 * 50];
    const int bid = blockIdx.x, tid = threadIdx.x;

    if (bid < 11456) {
        const int tStart[12] = {0,608,1120,2144,3168,3680,4704,5728,6752,7776,9408,11456};
        const int tK[11]  = {600,512,1024,1024,512,1024,1024,1024,1024,1624,1024};
        const int tN[11]  = {1024,1024,1024,1024,1024,1024,1024,1024,1024,1024,2001};
        const int tKp[11] = {608,512,1024,1024,512,1024,1024,1024,1024,1632,1024};
        const int tNp[11] = {1024,1024,1024,1024,1024,1024,1024,1024,1024,1024,2048};
        const long tDst[11] = {(long)O_QC,(long)O_AV,(long)O_AQQN,(long)(O_AQQN+1048576),
                               (long)O_VN,(long)O_QKV,(long)(O_QKV+1048576),
                               (long)(O_QKV+2097152),(long)O_WO,(long)O_UQC,(long)O_CLS};
        int e = 0;
        while (bid >= tStart[e + 1]) e++;
        const int local = bid - tStart[e];
        const int ktiles = tKp[e] >> 5;
        const int bx = local % ktiles, by = local / ktiles;
        const float* W = ps.s[e];
        u16* Wt = wt + tDst[e];
        const int K = tK[e], Nn = tN[e], Kp = tKp[e], Np = tNp[e];
        const int kt = bx * 32, nt = by * 32;
        const int tx = tid & 31, ty = tid >> 5;
        for (int i = ty; i < 32; i += 8) {
            const int k = kt + i, n = nt + tx;
            sm[i * 33 + tx] = (k < K && n < Nn) ? W[(size_t)k * Nn + n] : 0.f;
        }
        __syncthreads();
        for (int i = ty; i < 32; i += 8) {
            const int n = nt + i, k = kt + tx;
            if (n < Np && k < Kp) Wt[(size_t)n * Kp + k] = f2b(sm[tx * 33 + i]);
        }
    } else if (bid < 15104) {
        const int idx = (bid - 11456) * 256 + tid;          // NN*608 exactly
        const int n = idx / 608;
        const int col = idx - n * 608;
        const int b = n / Rr, r = n - b * Rr;
        float v = 0.f;
        if (col < Ee)          v = verb_table[(size_t)gt_verb[b] * Ee + col];
        else if (col < 2 * Ee) v = role_table[(size_t)role_idx[b * Rr + r] * Ee + (col - Ee)];
        cat[(size_t)n * 1632 + 1024 + col] = f2b(v);
    } else if (bid < 17152) {
        const int local = bid - 15104;
        const int b = local >> 3, c0 = (local & 7) << 6;
        {
            const int ci = tid >> 2, k0 = tid & 3;
            const float* p = v_org + ((size_t)b * Cc + c0 + ci) * Ksp;
            for (int k = k0; k < Ksp; k += 4) sm[ci * 50 + k] = p[k];
        }
        __syncthreads();
        {
            const int cc = tid & 63, kb = tid >> 6;
            for (int k = kb; k < Ksp; k += 4)
                A1[((size_t)b * Ksp + k) * Cc + c0 + cc] = f2b(sm[cc * 50 + k]);
        }
    } else if (bid < 23424) {
        const int i = (bid - 17152) * 256 + tid;            // 12544*512/4 exactly
        const float4 v = ((const float4*)img_feat)[i];
        ushort4 o;
        o.x = f2b(v.x); o.y = f2b(v.y); o.z = f2b(v.z); o.w = f2b(v.w);
        ((ushort4*)A2)[i] = o;
    } else {
        const int i = (bid - 23424) * 256 + tid;
        if (i < 2048) aqqn_b[i] = (i < 1024) ? aq_b[i] : qn_b[i - 1024];
    }
}

// ---------------- batch-level fused attention ----------------
// One block per batch. Logits via MFMA (49x6 over K=1024), softmax, then
// weighted sum over bf16 image rows for all 6 roles at once.
__global__ void __launch_bounds__(256) att_kernel(
    const u16* __restrict__ Vh,    // [B*49][1024] bf16
    const u16* __restrict__ Q,     // [NN][1024] bf16 (q_att)
    const float* __restrict__ aoW, const float* __restrict__ aoB,
    const u16* __restrict__ IMGb,  // [B*49][512] bf16
    u16* __restrict__ Vemb)        // [NN][512] bf16
{
    const int b = blockIdx.x;
    const int tid = threadIdx.x, wave = tid >> 6, lane = tid & 63;
    __shared__ u16 s_qs[16][1032];    // B-operand; 1032 = 129x16B rows -> conflict-free
    __shared__ float s_log[64][6];
    __shared__ float s_att[49][6];

    // stage Qs = q_att * aoW as bf16 (rows 6..15 zero)
    for (int n = 0; n < 16; n++) {
        const u16* qp = Q + ((size_t)b * Rr + n) * Hh;
        for (int h = tid; h < 1032; h += 256) {
            u16 v = 0;
            if (n < Rr && h < Hh) v = f2b(b2f(qp[h]) * aoW[h]);
            s_qs[n][h] = v;
        }
    }
    __syncthreads();

    // logits: wave w owns rows [w*16, w*16+16) of the 49 (rows>=49 discarded)
    const int m = lane & 15, q = lane >> 4;
    {
        f32x4 acc = (f32x4){0.f, 0.f, 0.f, 0.f};
        const u16* arow = Vh + ((size_t)b * Ksp + wave * 16 + m) * Hh + q * 8;
        const u16* brow = &s_qs[m][q * 8];
        for (int kt = 0; kt < Hh; kt += 32) {
            const short8 af = *(const short8*)(arow + kt);
            const short8 bf = *(const short8*)(brow + kt);
            acc = __builtin_amdgcn_mfma_f32_16x16x32_bf16(af, bf, acc, 0, 0, 0);
        }
        const float aob = aoB[0];
        #pragma unroll
        for (int r = 0; r < 4; r++) {
            const int k = wave * 16 + q * 4 + r;   // C/D: col=lane&15, row=q*4+r
            if (k < Ksp && m < Rr) s_log[k][m] = acc[r] + aob;
        }
    }
    __syncthreads();

    if (wave == 0) {
        for (int r = 0; r < Rr; r++) {
            const float v = (lane < Ksp) ? s_log[lane][r] : -INFINITY;
            float mx = v;
            #pragma unroll
            for (int off = 32; off; off >>= 1) mx = fmaxf(mx, __shfl_down(mx, off));
            mx = __shfl(mx, 0);
            const float e = (lane < Ksp) ? expf(v - mx) : 0.f;
            float s = e;
            #pragma unroll
            for (int off = 32; off; off >>= 1) s += __shfl_down(s, off);
            s = __shfl(s, 0);
            if (lane < Ksp) s_att[lane][r] = e / s;
        }
    }
    __syncthreads();

    // weighted sum: thread owns channels 2t,2t+1 for all 6 roles
    float acc2[Rr][2];
    #pragma unroll
    for (int r = 0; r < Rr; r++) { acc2[r][0] = 0.f; acc2[r][1] = 0.f; }
    const u16* ib = IMGb + (size_t)b * Ksp * Cc + tid * 2;
    #pragma unroll 7
    for (int k = 0; k < Ksp; k++) {
        const ushort2 v = *(const ushort2*)(ib + (size_t)k * Cc);
        const float v0 = b2f(v.x), v1 = b2f(v.y);
        #pragma unroll
        for (int r = 0; r < Rr; r++) {
            const float w = s_att[k][r];
            acc2[r][0] += w * v0; acc2[r][1] += w * v1;
        }
    }
    #pragma unroll
    for (int r = 0; r < Rr; r++) {
        ushort2 o; o.x = f2b(acc2[r][0]); o.y = f2b(acc2[r][1]);
        *(ushort2*)(Vemb + ((size_t)b * Rr + r) * Cc + tid * 2) = o;
    }
}

// ---------------- MFB: signed-sqrt + L2 norm; fp32 out + optional bf16 ----
__global__ void __launch_bounds__(256) mfb_kernel(
    const float* __restrict__ q, const float* __restrict__ v,
    float* __restrict__ outf, u16* __restrict__ outb)
{
    const int n = blockIdx.x;
    const int tid = threadIdx.x;
    __shared__ float red[4];
    float sv[4];
    float local = 0.f;
    #pragma unroll
    for (int i = 0; i < 4; i++) {
        const int h = tid + i * 256;
        const float z = q[(size_t)n * Hh + h] * v[(size_t)n * Hh + h];
        const float s = (z > 0.f) ? sqrtf(z) : -sqrtf(-z);
        sv[i] = s;
        local += s * s;
    }
    #pragma unroll
    for (int off = 32; off; off >>= 1) local += __shfl_down(local, off);
    if ((tid & 63) == 0) red[tid >> 6] = local;
    __syncthreads();
    const float tot = red[0] + red[1] + red[2] + red[3];
    const float inv = 1.f / fmaxf(sqrtf(tot), 1e-12f);
    #pragma unroll
    for (int i = 0; i < 4; i++) {
        const float o = sv[i] * inv;
        const size_t off2 = (size_t)n * Hh + tid + i * 256;
        outf[off2] = o;
        if (outb) outb[off2] = f2b(o);
    }
}

// ---------------- MFB(out2) + gate + tanh mix fused -> bf16 out_f ---------
__global__ void __launch_bounds__(256) mfb_gate_kernel(
    const float* __restrict__ q, const float* __restrict__ v,
    const float* __restrict__ ovb, const float* __restrict__ oa0,
    u16* __restrict__ outb)
{
    const int n = blockIdx.x;
    const int tid = threadIdx.x;
    __shared__ float red[4];
    float sv[4];
    float local = 0.f;
    #pragma unroll
    for (int i = 0; i < 4; i++) {
        const int h = tid + i * 256;
        const float z = q[(size_t)n * Hh + h] * v[(size_t)n * Hh + h];
        const float s = (z > 0.f) ? sqrtf(z) : -sqrtf(-z);
        sv[i] = s;
        local += s * s;
    }
    #pragma unroll
    for (int off = 32; off; off >>= 1) local += __shfl_down(local, off);
    if ((tid & 63) == 0) red[tid >> 6] = local;
    __syncthreads();
    const float tot = red[0] + red[1] + red[2] + red[3];
    const float inv = 1.f / fmaxf(sqrtf(tot), 1e-12f);
    #pragma unroll
    for (int i = 0; i < 4; i++) {
        const size_t off2 = (size_t)n * Hh + tid + i * 256;
        const float o2 = sv[i] * inv;
        const float ov = ovb[off2], a0 = oa0[off2];
        const float g = 1.f / (1.f + expf(-(o2 + ov)));
        outb[off2] = f2b((1.f - g) * ov + g * tanhf(o2 + a0));
    }
}

// ---------------- neighbor attention (reads fused qkv [NN][3072]) ---------
__global__ void __launch_bounds__(256) nattn_kernel(
    const float* __restrict__ qkv, const int* __restrict__ mask,
    u16* __restrict__ nv)
{
    const int b = blockIdx.x;
    const int tid = threadIdx.x;
    __shared__ float s_sc[Rr][Rr];
    __shared__ float s_at[Rr][Rr];
    const int wave = tid >> 6, lane = tid & 63;
    for (int p = wave; p < Rr * Rr; p += 4) {
        const int i = p / Rr, j = p - (p / Rr) * Rr;
        const float* qp = qkv + ((size_t)(b * Rr + i)) * 3072;
        const float* kp = qkv + ((size_t)(b * Rr + j)) * 3072 + 1024;
        float s = 0.f;
        for (int h = lane; h < Hh; h += 64) s += qp[h] * kp[h];
        #pragma unroll
        for (int off = 32; off; off >>= 1) s += __shfl_down(s, off);
        if (lane == 0) s_sc[i][j] = s * 0.03125f;   // 1/sqrt(1024)
    }
    __syncthreads();
    if (tid < Rr) {
        const int i = tid;
        float vals[Rr];
        float m = -INFINITY;
        #pragma unroll
        for (int j = 0; j < Rr; j++) {
            const float mij = (i == j) ? 0.f : (float)mask[b * Rr * Rr + i * Rr + j];
            const float v = (mij > 0.f) ? s_sc[i][j] : -1e9f;
            vals[j] = v;
            m = fmaxf(m, v);
        }
        float ssum = 0.f;
        #pragma unroll
        for (int j = 0; j < Rr; j++) { const float e = expf(vals[j] - m); s_at[i][j] = e; ssum += e; }
        const float invs = 1.f / ssum;
        #pragma unroll
        for (int j = 0; j < Rr; j++) s_at[i][j] *= invs;
    }
    __syncthreads();
    for (int h = tid; h < Hh; h += 256) {
        #pragma unroll
        for (int i = 0; i < Rr; i++) {
            float acc = 0.f;
            #pragma unroll
            for (int j = 0; j < Rr; j++)
                acc += s_at[i][j] * qkv[((size_t)(b * Rr + j)) * 3072 + 2048 + h];
            nv[((size_t)(b * Rr + i)) * Hh + h] = f2b(acc);
        }
    }
}

extern "C" void kernel_launch(void* const* d_in, const int* in_sizes, int n_in,
                              void* d_out, int out_size, void* d_ws, size_t ws_size,
                              hipStream_t stream)
{
    const float* v_org      = (const float*)d_in[0];
    const float* img_feat   = (const float*)d_in[1];
    const int*   gt_verb    = (const int*)d_in[2];
    const int*   role_idx   = (const int*)d_in[3];
    const int*   mask       = (const int*)d_in[4];
    const float* verb_table = (const float*)d_in[5];
    const float* role_table = (const float*)d_in[6];
    const float* qc_W  = (const float*)d_in[7];
    const float* qc_b  = (const float*)d_in[8];
    const float* av_W  = (const float*)d_in[9];
    const float* av_b  = (const float*)d_in[10];
    const float* aq_W  = (const float*)d_in[11];
    const float* aq_b  = (const float*)d_in[12];
    const float* ao_W  = (const float*)d_in[13];
    const float* ao_b  = (const float*)d_in[14];
    const float* vn_W  = (const float*)d_in[15];
    const float* vn_b  = (const float*)d_in[16];
    const float* qn_W  = (const float*)d_in[17];
    const float* qn_b  = (const float*)d_in[18];
    const float* Wq    = (const float*)d_in[19];
    const float* Wk    = (const float*)d_in[20];
    const float* Wv    = (const float*)d_in[21];
    const float* Wo    = (const float*)d_in[22];
    const float* uqc_W = (const float*)d_in[23];
    const float* uqc_b = (const float*)d_in[24];
    const float* cls_W = (const float*)d_in[25];
    const float* cls_b = (const float*)d_in[26];
    float* out = (float*)d_out;

    // ---- workspace layout ----
    char* base = (char*)d_ws;
    size_t off = 0;
    auto alloc = [&](size_t bytes) -> char* {
        char* p = base + off;
        off += (bytes + 255) & ~(size_t)255;
        return p;
    };
    u16* wt = (u16*)alloc(WT_ELEMS * 2);                       // 22.4 MB
    // P1: A1 [12544][512] + A2 [12544][512] contiguous (also big-GEMM A)
    u16* A1 = (u16*)alloc((size_t)12544 * 512 * 2 * 2);
    u16* A2 = A1 + (size_t)12544 * 512;
    // v_img + v_imgv contiguous (big-GEMM writes both as one M=25088 output)
    u16* v_img  = (u16*)alloc((size_t)12544 * 1024 * 2);
    char* P2    = alloc((size_t)12544 * 1024 * 2);
    u16* v_imgv = (u16*)P2;
    u16* nv     = (u16*)P2;                                    // after att_v
    float* qkv  = (float*)(P2 + 3145728);                      // dead after nattn
    u16* uq     = (u16*)(P2 + 3145728);                        // written after nattn
    u16* out_f  = (u16*)(P2 + 6291456);
    u16* cat    = (u16*)alloc((size_t)NN * 1632 * 2);          // [neigh|rv|pad]
    u16* q_emb  = (u16*)alloc((size_t)NN * 1024 * 2);
    u16* q_att  = (u16*)alloc((size_t)NN * 1024 * 2);
    u16* v_emb  = (u16*)alloc((size_t)NN * 512 * 2);
    float* q_rep = (float*)alloc((size_t)NN * 1024 * 4);
    float* v_rep = (float*)alloc((size_t)NN * 1024 * 4);
    float* a0f   = (float*)alloc((size_t)NN * 1024 * 4);
    u16*   a0b   = (u16*)alloc((size_t)NN * 1024 * 2);
    float* vbf   = (float*)alloc((size_t)NN * 1024 * 4);
    float* aqqn_b = (float*)alloc(2048 * 4);

    const dim3 blk(256);

    // 1. unified prep: 11 transposes + rv gather + img0 transpose + imgf cast + bias fuse
    PrepSrc ps;
    ps.s[0] = qc_W;  ps.s[1] = av_W; ps.s[2] = aq_W; ps.s[3] = qn_W;
    ps.s[4] = vn_W;  ps.s[5] = Wq;   ps.s[6] = Wk;   ps.s[7] = Wv;
    ps.s[8] = Wo;    ps.s[9] = uqc_W; ps.s[10] = cls_W;
    prep_kernel<<<dim3(23432), blk, 0, stream>>>(
        ps, wt, verb_table, role_table, gt_verb, role_idx, cat,
        v_org, A1, img_feat, A2, aq_b, qn_b, aqqn_b);

    // 2. q_emb = relu(rv @ qc_W + b)   (rv lives in cat cols 1024.., lda=1632)
    gemm_bf16<2,2><<<dim3(16, 24), blk, 0, stream>>>(
        cat + 1024, 1632, wt + O_QC, qc_b, q_emb, 1024, nullptr, 0,
        1024, 608, 1024, 1024, 1);
    // 3. [v_img; v_imgv] = relu([img0; img_feat] @ av_W + b), M=25088
    gemm_bf16<4,4><<<dim3(8, 196), blk, 0, stream>>>(
        A1, 512, wt + O_AV, av_b, v_img, 1024, nullptr, 0,
        1024, 512, 1024, 1024, 1);
    // 4. fused: q_att(bf16) | q_rep(fp32) = relu(q_emb @ [aq|qn] + b)
    gemm_bf16<2,2><<<dim3(32, 24), blk, 0, stream>>>(
        q_emb, 1024, wt + O_AQQN, aqqn_b, q_att, 1024, q_rep, 1024,
        2048, 1024, 1024, 2048, 1);
    // 5. att1 -> v_emb
    att_kernel<<<dim3(Bb), blk, 0, stream>>>(v_img, q_att, ao_W, ao_b, A1, v_emb);
    // 6. v_rep = relu(v_emb @ vn + b)  (fp32)
    gemm_bf16<2,2><<<dim3(16, 24), blk, 0, stream>>>(
        v_emb, 512, wt + O_VN, vn_b, nullptr, 0, v_rep, 1024,
        1024, 512, 0, 1024, 1);
    // 7. ans0 = MFB(q_rep, v_rep) -> a0f + a0b
    mfb_kernel<<<dim3(NN), blk, 0, stream>>>(q_rep, v_rep, a0f, a0b);
    // 8. att_v -> v_emb
    att_kernel<<<dim3(Bb), blk, 0, stream>>>(v_imgv, q_att, ao_W, ao_b, A2, v_emb);
    gemm_bf16<2,2><<<dim3(16, 24), blk, 0, stream>>>(
        v_emb, 512, wt + O_VN, vn_b, nullptr, 0, v_rep, 1024,
        1024, 512, 0, 1024, 1);
    // 9. out_verb = MFB(q_rep, v_rep) -> vbf
    mfb_kernel<<<dim3(NN), blk, 0, stream>>>(q_rep, v_rep, vbf, nullptr);
    // 10. qkv = ans0 @ [Wq|Wk|Wv]  (fp32, in P2 past nv region)
    gemm_bf16<2,2><<<dim3(48, 24), blk, 0, stream>>>(
        a0b, 1024, wt + O_QKV, nullptr, nullptr, 0, qkv, 3072,
        3072, 1024, 0, 3072, 0);
    // 11. neighbor attention -> nv (bf16)
    nattn_kernel<<<dim3(Bb), blk, 0, stream>>>(qkv, mask, nv);
    // 12. neigh = nv @ Wo -> cat cols 0..1023 (ldc=1632)
    gemm_bf16<2,2><<<dim3(16, 24), blk, 0, stream>>>(
        nv, 1024, wt + O_WO, nullptr, cat, 1632, nullptr, 0,
        1024, 1024, 1024, 1024, 0);
    // 13. uq = relu(cat @ uqc + b), K=1632
    gemm_bf16<2,2><<<dim3(16, 24), blk, 0, stream>>>(
        cat, 1632, wt + O_UQC, uqc_b, uq, 1024, nullptr, 0,
        1024, 1632, 1024, 1024, 1);
    // 14. fused: q_att2 | q_rep2 = relu(uq @ [aq|qn] + b)
    gemm_bf16<2,2><<<dim3(32, 24), blk, 0, stream>>>(
        uq, 1024, wt + O_AQQN, aqqn_b, q_att, 1024, q_rep, 1024,
        2048, 1024, 1024, 2048, 1);
    // 15. att2 -> v_emb
    att_kernel<<<dim3(Bb), blk, 0, stream>>>(v_img, q_att, ao_W, ao_b, A1, v_emb);
    gemm_bf16<2,2><<<dim3(16, 24), blk, 0, stream>>>(
        v_emb, 512, wt + O_VN, vn_b, nullptr, 0, v_rep, 1024,
        1024, 512, 0, 1024, 1);
    // 16. out2 = MFB(q_rep2, v_rep2); gate with out_verb/ans0 -> out_f (bf16)
    mfb_gate_kernel<<<dim3(NN), blk, 0, stream>>>(q_rep, v_rep, vbf, a0f, out_f);
    // 17. logits = out_f @ cls_W + b -> d_out fp32 [1536][2001]
    gemm_bf16<2,2><<<dim3(32, 24), blk, 0, stream>>>(
        out_f, 1024, wt + O_CLS, cls_b, nullptr, 0, out, 2001,
        2048, 1024, 0, 2001, 0);
}